// Round 7
// baseline (764.760 us; speedup 1.0000x reference)
//
#include <hip/hip_runtime.h>

// CovariantEvolutionBlock on MI355X (gfx950).
// I/O is float32 (bf16-grid values); internal compute bf16 MFMA + fp32 accum.
// B=2, L=2048, D=1024, H=16, HD=64, N=B*L=4096 tokens.

typedef unsigned short u16;
typedef __attribute__((ext_vector_type(8))) short short8;
typedef __attribute__((ext_vector_type(8))) unsigned short us8;
typedef __attribute__((ext_vector_type(4))) float f32x4;
typedef __attribute__((ext_vector_type(4))) unsigned short us4;
typedef __attribute__((ext_vector_type(2))) unsigned int u32x2;

__device__ __forceinline__ float b2f(u16 u) {
    union { unsigned u; float f; } c; c.u = ((unsigned)u) << 16; return c.f;
}
__device__ __forceinline__ u16 f2b(float f) {
    union { float f; unsigned u; } c; c.f = f;
    unsigned x = c.u;
    unsigned r = (x + 0x7fffu + ((x >> 16) & 1u)) >> 16;   // RNE
    return (u16)r;
}
__device__ __forceinline__ float fast_rcp(float x) {
    return __builtin_amdgcn_rcpf(x);     // v_rcp_f32, ~1 ulp, fine pre-bf16
}
// HW packed f32->bf16 (RNE), 1 instruction for 2 values.
__device__ __forceinline__ unsigned cvt_pk_bf16(float a, float b) {
    unsigned r;
    asm("v_cvt_pk_bf16_f32 %0, %1, %2" : "=v"(r) : "v"(a), "v"(b));
    return r;
}

__device__ __forceinline__ void async_copy16(const u16* g, u16* l) {
    __builtin_amdgcn_global_load_lds(
        (const __attribute__((address_space(1))) unsigned int*)(g),
        (__attribute__((address_space(3))) unsigned int*)(l), 16, 0, 0);
}

// ---------------------------------------------------------------------------
// fp32 -> bf16 conversion, 4 elems/thread. n must be a multiple of 1024.
__global__ __launch_bounds__(256) void cvt_k(const float* __restrict__ s,
                                             u16* __restrict__ d, int n) {
    int i = (blockIdx.x * 256 + threadIdx.x) * 4;
    if (i >= n) return;
    f32x4 v = *(const f32x4*)(s + i);
    us4 o;
#pragma unroll
    for (int k = 0; k < 4; k++) o[k] = f2b(v[k]);
    *(us4*)(d + i) = o;
}

// ---------------------------------------------------------------------------
// RMSNorm from fp32 input: one block per token, D=1024, 256 threads x 4 contig.
// Optional cp: raw fp32 copy-out (folds z_before). Optional cb: raw bf16
// copy-out (folds the conn->bf16 cvt into the conn RMSNorm pass).
__global__ __launch_bounds__(256) void rmsf_k(const float* __restrict__ x,
                                              const float* __restrict__ w,
                                              u16* __restrict__ y,
                                              float* __restrict__ cp,
                                              u16* __restrict__ cb, int D) {
    int n = blockIdx.x;
    const float* xr = x + (size_t)n * D;
    int i0 = threadIdx.x << 2;
    f32x4 v = *(const f32x4*)(xr + i0);
    if (cp) *(f32x4*)(cp + (size_t)n * D + i0) = v;
    if (cb) {
        us4 o2;
#pragma unroll
        for (int k = 0; k < 4; k++) o2[k] = f2b(v[k]);
        *(us4*)(cb + (size_t)n * D + i0) = o2;
    }
    float s = v[0] * v[0] + v[1] * v[1] + v[2] * v[2] + v[3] * v[3];
#pragma unroll
    for (int m = 32; m >= 1; m >>= 1) s += __shfl_xor(s, m, 64);
    __shared__ float red[4];
    if ((threadIdx.x & 63) == 0) red[threadIdx.x >> 6] = s;
    __syncthreads();
    float tot = red[0] + red[1] + red[2] + red[3];
    float scale = rsqrtf(tot / (float)D + 1e-6f);
    f32x4 wv = *(const f32x4*)(w + i0);
    us4 o;
#pragma unroll
    for (int k = 0; k < 4; k++) o[k] = f2b(v[k] * scale * wv[k]);
    *(us4*)(y + (size_t)n * D + i0) = o;
}

// RMSNorm from bf16 (internal) input.
__global__ __launch_bounds__(256) void rmsb_k(const u16* __restrict__ x,
                                              const float* __restrict__ w,
                                              u16* __restrict__ y, int D) {
    int n = blockIdx.x;
    const u16* xr = x + (size_t)n * D;
    int i0 = threadIdx.x << 2;
    us4 xv = *(const us4*)(xr + i0);
    float v[4]; float s = 0.f;
#pragma unroll
    for (int k = 0; k < 4; k++) { v[k] = b2f(xv[k]); s += v[k] * v[k]; }
#pragma unroll
    for (int m = 32; m >= 1; m >>= 1) s += __shfl_xor(s, m, 64);
    __shared__ float red[4];
    if ((threadIdx.x & 63) == 0) red[threadIdx.x >> 6] = s;
    __syncthreads();
    float tot = red[0] + red[1] + red[2] + red[3];
    float scale = rsqrtf(tot / (float)D + 1e-6f);
    f32x4 wv = *(const f32x4*)(w + i0);
    us4 o;
#pragma unroll
    for (int k = 0; k < 4; k++) o[k] = f2b(v[k] * scale * wv[k]);
    *(us4*)(y + (size_t)n * D + i0) = o;
}

// ---------------------------------------------------------------------------
// Tiled NT GEMM: C[n,o] = epi(act(sum_k A[n,k]*W[o,k] + bias[o])).
// BM x BN tile (BM,BN in {64,128}), BK=64, 4 waves (2x2), global_load_lds
// staging with XOR-swizzled (8-group) source addressing, LDS double-buffer,
// ONE barrier per 64-wide K-step. Bijective XCD-aware block swizzle.
// Occupancy: 64x64 -> 32KB LDS, grid 1024 = 4 blocks/CU (O=1024 shapes);
//            128x64 -> 48KB LDS, 3 blocks/CU (O=2048/4096 shapes).
// A-operand is a virtual concat of NSEG segments (native row stride 1024).
// act: 0=none 1=silu 2=tanh.
// mode (epilogue): 0 = C[idx]=bf16(v)
//   1 = per-head V-transpose: VT[((b*16+h)*64+d)*2048+tok]
//   2 = dz:   C[idx] = bf16(sc[0] * (b2f(Eb[idx]) + v))       (g_w2)
//   3 = z1:   C[idx] = bf16(Ef[idx] + b2f(Eb[idx]) + v)       (o_w)
//   4 = conn: Cf[idx] = Ef[idx] + v                           (cu_w2)
//   5 = z2:   Cf[idx] = b2f(Eb[idx]) + v                      (m_w2)
template <int BM, int BN, int NSEG>
__global__ __launch_bounds__(256) void gemm_t(const u16* __restrict__ A0,
                                              const u16* __restrict__ A1,
                                              const u16* __restrict__ A2,
                                              const u16* __restrict__ W,
                                              const float* __restrict__ bias,
                                              u16* __restrict__ C,
                                              const u16* __restrict__ Eb,
                                              const float* __restrict__ Ef,
                                              const float* __restrict__ sc,
                                              float* __restrict__ Cf,
                                              int K, int O, int act, int mode) {
    constexpr int WM = BM / 2, WN = BN / 2;      // wave tile
    constexpr int NI = WM / 16, NJ = WN / 16;    // fragment repeats
    __shared__ u16 Asm[2][BM * 64];
    __shared__ u16 Bsm[2][BN * 64];

    const int tid = threadIdx.x;
    const int wid = tid >> 6, lane = tid & 63;
    const int l15 = lane & 15, quad = lane >> 4;
    const int lsw = l15 & 7;

    // XCD-aware bijective swizzle (requires nwg % 8 == 0, true for all shapes).
    const int nwg = gridDim.x * gridDim.y;
    int id = blockIdx.y * gridDim.x + blockIdx.x;
    id = (id & 7) * (nwg >> 3) + (id >> 3);
    const int bx = id % gridDim.x, by = id / gridDim.x;

    const int row0 = by * BM, col0 = bx * BN;
    const int wm = (wid >> 1) * WM, wn = (wid & 1) * WN;

    // Staging: slot s: row r=s>>3, group g=s&7; LDS[r][g] holds source group
    // g^(r&7) (linear dest, pre-swizzled per-lane source). Each call-line of
    // 256 threads covers 32 rows x 64 cols.
    const int rb = tid >> 3;                       // 0..31
    const int gg = ((tid & 7) ^ (rb & 7)) << 3;    // source col offset, elems
    const int sA = (NSEG == 1) ? K : 1024;         // A row stride
    const size_t aoff = (size_t)(row0 + rb) * sA + gg;
    const size_t boff = (size_t)(col0 + rb) * K + gg;
    const int ldsb = wid << 9;                     // wave base within call-line

    f32x4 acc[NI][NJ];
#pragma unroll
    for (int i = 0; i < NI; i++)
#pragma unroll
        for (int j = 0; j < NJ; j++) acc[i][j] = (f32x4){0.f, 0.f, 0.f, 0.f};

    auto stage = [&](int buf, int kof) {
        const u16* Ab; int kcol;
        if constexpr (NSEG == 1) { Ab = A0; kcol = kof; }
        else {
            int seg = kof >> 10;                   // BK=64 never crosses a seg
            Ab = (seg == 0) ? A0 : ((NSEG == 3 && seg == 2) ? A2 : A1);
            kcol = kof & 1023;
        }
        const u16* as = Ab + aoff + kcol;
        const u16* bs = W + boff + kof;
#pragma unroll
        for (int i = 0; i < BM / 32; i++)
            async_copy16(as + (size_t)(32 * i) * sA, &Asm[buf][(i << 11) + ldsb]);
#pragma unroll
        for (int i = 0; i < BN / 32; i++)
            async_copy16(bs + (size_t)(32 * i) * K, &Bsm[buf][(i << 11) + ldsb]);
    };

    const int nk = K >> 6;
    stage(0, 0);
    __syncthreads();
    for (int kk = 0; kk < nk; kk++) {
        int cur = kk & 1;
        if (kk + 1 < nk) stage(1 - cur, (kk + 1) << 6);
        const u16* Ab = Asm[cur];
        const u16* Bb = Bsm[cur];
#pragma unroll
        for (int h = 0; h < 2; h++) {
            const int gq = (((h << 2) + quad) ^ lsw) << 3;
            short8 af[NI], bf[NJ];
#pragma unroll
            for (int i = 0; i < NI; i++)
                af[i] = *(const short8*)&Ab[(wm + i * 16 + l15) * 64 + gq];
#pragma unroll
            for (int j = 0; j < NJ; j++)
                bf[j] = *(const short8*)&Bb[(wn + j * 16 + l15) * 64 + gq];
#pragma unroll
            for (int i = 0; i < NI; i++)
#pragma unroll
                for (int j = 0; j < NJ; j++)
                    acc[i][j] = __builtin_amdgcn_mfma_f32_16x16x32_bf16(af[i], bf[j], acc[i][j], 0, 0, 0);
        }
        __syncthreads();
    }

    if (mode == 1) {
        // V-transpose epilogue: 4 consecutive toks -> one 8B store VT[bh][d][tok].
#pragma unroll
        for (int j = 0; j < NJ; j++) {
            int col = col0 + wn + j * 16 + l15;     // h*64 + d
            int h = col >> 6, d = col & 63;
#pragma unroll
            for (int i = 0; i < NI; i++) {
                int rowb = row0 + wm + i * 16 + (quad << 2);
                int bb_ = rowb >> 11;               // batch
                int tok = rowb & 2047;
                u32x2 pk2;
                pk2[0] = cvt_pk_bf16(acc[i][j][0], acc[i][j][1]);
                pk2[1] = cvt_pk_bf16(acc[i][j][2], acc[i][j][3]);
                *(u32x2*)&C[(size_t)(((bb_ << 4) + h) * 64 + d) * 2048 + tok] = pk2;
            }
        }
    } else {
        float dtv = (mode == 2) ? sc[0] : 0.f;
#pragma unroll
        for (int j = 0; j < NJ; j++) {
            int col = col0 + wn + j * 16 + l15;
            float bb = bias ? bias[col] : 0.f;
#pragma unroll
            for (int i = 0; i < NI; i++) {
                int rowb = row0 + wm + i * 16 + (quad << 2);
#pragma unroll
                for (int g = 0; g < 4; g++) {
                    float v = acc[i][j][g] + bb;
                    if (act == 1) {                      // silu
                        v = v * fast_rcp(1.f + __expf(-v));
                    } else if (act == 2) {               // tanh = 1 - 2/(e^2x+1)
                        float t = __expf(v * 2.f);
                        v = 1.f - 2.f * fast_rcp(1.f + t);
                    }
                    size_t idx = (size_t)(rowb + g) * O + col;
                    if (mode == 0)      C[idx] = f2b(v);
                    else if (mode == 2) C[idx] = f2b(dtv * (b2f(Eb[idx]) + v));
                    else if (mode == 3) C[idx] = f2b(Ef[idx] + b2f(Eb[idx]) + v);
                    else if (mode == 4) Cf[idx] = Ef[idx] + v;
                    else                Cf[idx] = b2f(Eb[idx]) + v;
                }
            }
        }
    }
}

// ---------------------------------------------------------------------------
// Sigmoid attention v6: LDS-staged + XCD-swizzled blocks (proven R6 structure).
// Block = 256 thr = 4 waves = 128 queries of one (b,h); 64-key tiles, double-
// buffered, one barrier/iter. Swapped QK^T (mfma(K,Q)): lane holds 4
// consecutive keys of one q-row -> sigmoid + 2x cvt_pk + ONE ds_write_b64.
__global__ __launch_bounds__(256) void attn_k(const u16* __restrict__ QK,
                                              const u16* __restrict__ VT,
                                              const float* __restrict__ temp_p,
                                              u16* __restrict__ Oa) {
    const int L = 2048, D = 1024, SQ = 2048;
    __shared__ u16 Ks[2][64 * 64];
    __shared__ u16 Vs[2][64 * 64];
    __shared__ u16 plds[4][16 * 72];

    const int tid = threadIdx.x;
    const int w = tid >> 6, lane = tid & 63;
    const int l15 = lane & 15, quad = lane >> 4;
    int id = blockIdx.x;
    id = (id & 7) * 64 + (id >> 3);           // XCD swizzle: 4 bh per XCD
    const int bh = id >> 4;                   // 16 blocks per (b,h)
    const int qb0 = (id & 15) << 7;           // 128 queries per block
    const int b = bh >> 4, h = bh & 15;
    const float nsc2 = -0.125f * temp_p[0] * 1.44269504f;  // fold log2(e)

    // Q fragments: 2 q-tiles x 2 dim-halves (k=32 each).
    short8 aq[2][2];
#pragma unroll
    for (int qt = 0; qt < 2; qt++) {
        size_t row = (size_t)(b * L + qb0 + w * 32 + qt * 16 + l15) * SQ + h * 64;
#pragma unroll
        for (int hf = 0; hf < 2; hf++)
            aq[qt][hf] = *(const short8*)(QK + row + hf * 32 + quad * 8);
    }

    const u16* Kbase = QK + 1024 + (size_t)(b * L) * SQ + h * 64;
    const u16* VTb   = VT + (size_t)bh * 64 * L;

    // Staging: slot i (0..511): row r=i>>3, group gs=i&7, src group gs^(r&7).
    const int i0 = tid, i1 = tid + 256;
    const int r0 = i0 >> 3, g0 = (i0 & 7) ^ (r0 & 7);
    const int r1 = i1 >> 3, g1 = (i1 & 7) ^ (r1 & 7);
    const u16* kS0 = Kbase + (size_t)r0 * SQ + g0 * 8;
    const u16* kS1 = Kbase + (size_t)r1 * SQ + g1 * 8;
    const u16* vS0 = VTb + (size_t)r0 * L + g0 * 8;
    const u16* vS1 = VTb + (size_t)r1 * L + g1 * 8;

    auto stage = [&](int buf, int mc) {
        async_copy16(kS0 + (size_t)mc * SQ, &Ks[buf][w << 9]);
        async_copy16(kS1 + (size_t)mc * SQ, &Ks[buf][2048 + (w << 9)]);
        async_copy16(vS0 + mc, &Vs[buf][w << 9]);
        async_copy16(vS1 + mc, &Vs[buf][2048 + (w << 9)]);
    };

    f32x4 acc[2][4];
#pragma unroll
    for (int i = 0; i < 2; i++)
#pragma unroll
        for (int j = 0; j < 4; j++) acc[i][j] = (f32x4){0.f, 0.f, 0.f, 0.f};
    float rs[2] = {0.f, 0.f};
    u16* P = plds[w];
    const int lsw = l15 & 7;   // read-side swizzle key

    stage(0, 0);
    __syncthreads();
    for (int it = 0; it < 32; it++) {
        int cur = it & 1;
        if (it < 31) stage(1 - cur, (it + 1) << 6);
        const u16* Kt = Ks[cur];
        const u16* Vt = Vs[cur];
#pragma unroll
        for (int qt = 0; qt < 2; qt++) {
#pragma unroll
            for (int ks = 0; ks < 4; ks++) {
                f32x4 s = (f32x4){0.f, 0.f, 0.f, 0.f};
#pragma unroll
                for (int hf = 0; hf < 2; hf++) {
                    int slot = ((ks * 16 + l15) * 8 + ((hf * 4 + quad) ^ lsw)) * 8;
                    short8 bk = *(const short8*)&Kt[slot];
                    // swapped: A=K (row=key), B=Q (col=q)
                    s = __builtin_amdgcn_mfma_f32_16x16x32_bf16(bk, aq[qt][hf], s, 0, 0, 0);
                }
                float p0 = fast_rcp(1.f + __builtin_amdgcn_exp2f(s[0] * nsc2));
                float p1 = fast_rcp(1.f + __builtin_amdgcn_exp2f(s[1] * nsc2));
                float p2 = fast_rcp(1.f + __builtin_amdgcn_exp2f(s[2] * nsc2));
                float p3 = fast_rcp(1.f + __builtin_amdgcn_exp2f(s[3] * nsc2));
                rs[qt] += (p0 + p1) + (p2 + p3);
                u32x2 pk2;
                pk2[0] = cvt_pk_bf16(p0, p1);
                pk2[1] = cvt_pk_bf16(p2, p3);
                // P[q = l15][key = ks*16 + quad*4 .. +3], 8B aligned store
                *(u32x2*)&P[l15 * 72 + ks * 16 + (quad << 2)] = pk2;
            }
#pragma unroll
            for (int kh = 0; kh < 2; kh++) {
                short8 ap = *(const short8*)&P[l15 * 72 + kh * 32 + quad * 8];
#pragma unroll
                for (int dt = 0; dt < 4; dt++) {
                    int slot = ((dt * 16 + l15) * 8 + ((kh * 4 + quad) ^ lsw)) * 8;
                    short8 bv = *(const short8*)&Vt[slot];
                    acc[qt][dt] = __builtin_amdgcn_mfma_f32_16x16x32_bf16(ap, bv, acc[qt][dt], 0, 0, 0);
                }
            }
        }
        __syncthreads();
    }

    // rs: per-lane partial over its quad's keys; reduce across quad dimension.
#pragma unroll
    for (int qt = 0; qt < 2; qt++) {
        rs[qt] += __shfl_xor(rs[qt], 16, 64);
        rs[qt] += __shfl_xor(rs[qt], 32, 64);
    }

#pragma unroll
    for (int qt = 0; qt < 2; qt++) {
        u16* orow = Oa + (size_t)(b * L + qb0 + w * 32 + qt * 16) * D + h * 64;
#pragma unroll
        for (int g = 0; g < 4; g++) {
            int row = quad * 4 + g;
            float denom = __shfl(rs[qt], row, 64);   // lane 'row' holds q=row
            float rd = fast_rcp(fmaxf(denom, 1.0f));
#pragma unroll
            for (int dt = 0; dt < 4; dt++)
                orow[(size_t)row * D + dt * 16 + l15] = f2b(acc[qt][dt][g] * rd);
        }
    }
}

// ---------------------------------------------------------------------------
extern "C" void kernel_launch(void* const* d_in, const int* in_sizes, int n_in,
                              void* d_out, int out_size, void* d_ws, size_t ws_size,
                              hipStream_t stream) {
    const int B = 2, L = 2048, D = 1024, H = 16, N = B * L;
    const float* z      = (const float*)d_in[0];
    const float* conn   = (const float*)d_in[1];
    const float* w_z    = (const float*)d_in[2];
    const float* w_c    = (const float*)d_in[3];
    const float* w_mlp  = (const float*)d_in[4];
    const float* f_w1   = (const float*)d_in[5];
    const float* f_b1   = (const float*)d_in[6];
    const float* f_w2   = (const float*)d_in[7];
    const float* f_b2   = (const float*)d_in[8];
    const float* g_w1   = (const float*)d_in[9];
    const float* g_b1   = (const float*)d_in[10];
    const float* g_w2   = (const float*)d_in[11];
    const float* g_b2   = (const float*)d_in[12];
    const float* dt_p   = (const float*)d_in[13];
    const float* q_w    = (const float*)d_in[14];
    const float* k_w    = (const float*)d_in[15];
    const float* v_w    = (const float*)d_in[16];
    const float* o_w    = (const float*)d_in[17];
    const float* temp_p = (const float*)d_in[18];
    const float* cu_w1  = (const float*)d_in[19];
    const float* cu_b1  = (const float*)d_in[20];
    const float* cu_w2  = (const float*)d_in[21];
    const float* cu_b2  = (const float*)d_in[22];
    const float* m_w1   = (const float*)d_in[23];
    const float* m_b1   = (const float*)d_in[24];
    const float* m_w2   = (const float*)d_in[25];
    const float* m_b2   = (const float*)d_in[26];

    float* out = (float*)d_out;
    u16* ws  = (u16*)d_ws;
    const size_t U = (size_t)N * D;   // 4M elems

    // Activation slots (bf16), liveness-packed:
    // slot0: zn -> z1n         slot1: cn -> attnb -> mh[0]
    // slot2: h1[0] -> QK[0] -> cu_h[0] -> mh[1]
    // slot3: h1[1] -> QK[1] -> cu_h[1] -> mh[2]
    // slot4: dzl -> VT -> mh[3]
    // slot5: gh -> z1          slot6: dz          slot7: connb
    u16* zn    = ws + 0 * U;
    u16* cn    = ws + 1 * U;
    u16* h1    = ws + 2 * U;   // 2 units
    u16* dzl   = ws + 4 * U;
    u16* gh    = ws + 5 * U;
    u16* dz    = ws + 6 * U;
    u16* connb = ws + 7 * U;
    u16* QK    = ws + 2 * U;   // 2 units (h1 dead): [N][2048], Q|K
    u16* VT    = ws + 4 * U;   // dzl dead after g_w2 epi; VT[bh][64][L]
    u16* attnb = ws + 1 * U;   // cn dead after QK gemm
    u16* z1    = ws + 5 * U;   // gh dead after g_w2
    u16* cu_h  = ws + 2 * U;   // 2 units, QK dead after attn
    u16* z1n   = ws + 0 * U;   // zn dead after v_w
    u16* mh    = ws + 1 * U;   // 4 units (1-4): attnb, cu_h, VT dead

    // bf16 weight copies after activation slots: 29M u16 elems.
    u16* wb = ws + 9 * U;
    u16* bf_w1  = wb + 0;                       // 2M
    u16* bf_w2  = wb + 2 * 1024 * 1024;         // 2M
    u16* bg_w1  = wb + 4 * 1024 * 1024;         // 2M
    u16* bg_w2  = wb + 6 * 1024 * 1024;         // 1M
    u16* bqk_w  = wb + 7 * 1024 * 1024;         // 4M: q_w rows then k_w rows
    u16* bv_w   = wb + 11 * 1024 * 1024;        // 1M
    u16* bo_w   = wb + 12 * 1024 * 1024;        // 1M
    u16* bcu_w1 = wb + 13 * 1024 * 1024;        // 6M
    u16* bcu_w2 = wb + 19 * 1024 * 1024;        // 2M
    u16* bm_w1  = wb + 21 * 1024 * 1024;        // 4M
    u16* bm_w2  = wb + 25 * 1024 * 1024;        // 4M

    auto cvt = [&](const float* s, u16* d, int n) {
        cvt_k<<<n / 1024, 256, 0, stream>>>(s, d, n);
    };
    cvt(f_w1, bf_w1, 2 * D * D);   cvt(f_w2, bf_w2, 2 * D * D);
    cvt(g_w1, bg_w1, 2 * D * D);   cvt(g_w2, bg_w2, D * D);
    cvt(q_w, bqk_w, 2 * D * D);    cvt(k_w, bqk_w + 2 * D * D, 2 * D * D);
    cvt(v_w, bv_w, D * D);         cvt(o_w, bo_w, D * D);
    cvt(cu_w1, bcu_w1, 6 * D * D); cvt(cu_w2, bcu_w2, 2 * D * D);
    cvt(m_w1, bm_w1, 4 * D * D);   cvt(m_w2, bm_w2, 4 * D * D);

    rmsf_k<<<N, 256, 0, stream>>>(z, w_z, zn, out + 2 * U, nullptr, D);  // + z_before
    rmsf_k<<<N, 256, 0, stream>>>(conn, w_c, cn, nullptr, connb, D);     // + conn bf16

    const u16* nu = nullptr;
    // dz_local = f_w2(silu(f_w1(zn)))
    gemm_t<128, 64, 1><<<dim3(32, 32), 256, 0, stream>>>(
        zn, nu, nu, bf_w1, f_b1, h1, nu, nullptr, nullptr, nullptr, D, 2 * D, 1, 0);
    gemm_t<64, 64, 1><<<dim3(16, 64), 256, 0, stream>>>(
        h1, nu, nu, bf_w2, f_b2, dzl, nu, nullptr, nullptr, nullptr, 2 * D, D, 0, 0);
    // corr path; g_w2 epilogue writes dz = dt*(dzl + corr) directly (mode 2)
    gemm_t<64, 64, 2><<<dim3(16, 64), 256, 0, stream>>>(
        cn, dzl, nu, bg_w1, g_b1, gh, nu, nullptr, nullptr, nullptr, 2 * D, D, 2, 0);
    gemm_t<64, 64, 1><<<dim3(16, 64), 256, 0, stream>>>(
        gh, nu, nu, bg_w2, g_b2, dz, dzl, nullptr, dt_p, nullptr, D, D, 0, 2);

    // attention: fused Q|K, V-transpose, sigmoid attn, o-proj (+z1 fusion)
    gemm_t<128, 64, 2><<<dim3(32, 32), 256, 0, stream>>>(
        zn, cn, nu, bqk_w, nullptr, QK, nu, nullptr, nullptr, nullptr, 2 * D, 2 * D, 0, 0);
    gemm_t<64, 64, 1><<<dim3(16, 64), 256, 0, stream>>>(
        zn, nu, nu, bv_w, nullptr, VT, nu, nullptr, nullptr, nullptr, D, D, 0, 1);
    attn_k<<<B * H * L / 128, 256, 0, stream>>>(QK, VT, temp_p, attnb);
    gemm_t<64, 64, 1><<<dim3(16, 64), 256, 0, stream>>>(       // z1 = z + dz + ctx
        attnb, nu, nu, bo_w, nullptr, z1, dz, z, nullptr, nullptr, D, D, 0, 3);

    // connection update; cu_w2 epilogue writes conn_new (fp32) directly
    gemm_t<128, 64, 3><<<dim3(32, 32), 256, 0, stream>>>(
        connb, z1, dz, bcu_w1, cu_b1, cu_h, nu, nullptr, nullptr, nullptr, 3 * D, 2 * D, 1, 0);
    gemm_t<64, 64, 1><<<dim3(16, 64), 256, 0, stream>>>(
        cu_h, nu, nu, bcu_w2, cu_b2, nu == nullptr ? (u16*)nullptr : (u16*)nullptr,
        nu, conn, nullptr, out + U, 2 * D, D, 0, 4);

    // MLP block; m_w2 epilogue writes z2 (fp32) directly
    rmsb_k<<<N, 256, 0, stream>>>(z1, w_mlp, z1n, D);
    gemm_t<128, 64, 1><<<dim3(64, 32), 256, 0, stream>>>(
        z1n, nu, nu, bm_w1, m_b1, mh, nu, nullptr, nullptr, nullptr, D, 4 * D, 1, 0);
    gemm_t<64, 64, 1><<<dim3(16, 64), 256, 0, stream>>>(
        mh, nu, nu, bm_w2, m_b2, (u16*)nullptr, z1, nullptr, nullptr, out, 4 * D, D, 0, 5);
}

// Round 8
// 741.571 us; speedup vs baseline: 1.0313x; 1.0313x over previous
//
#include <hip/hip_runtime.h>

// CovariantEvolutionBlock on MI355X (gfx950).
// I/O is float32 (bf16-grid values); internal compute bf16 MFMA + fp32 accum.
// B=2, L=2048, D=1024, H=16, HD=64, N=B*L=4096 tokens.

typedef unsigned short u16;
typedef __attribute__((ext_vector_type(8))) short short8;
typedef __attribute__((ext_vector_type(8))) unsigned short us8;
typedef __attribute__((ext_vector_type(4))) float f32x4;
typedef __attribute__((ext_vector_type(4))) unsigned short us4;
typedef __attribute__((ext_vector_type(2))) unsigned int u32x2;

__device__ __forceinline__ float b2f(u16 u) {
    union { unsigned u; float f; } c; c.u = ((unsigned)u) << 16; return c.f;
}
__device__ __forceinline__ u16 f2b(float f) {
    union { float f; unsigned u; } c; c.f = f;
    unsigned x = c.u;
    unsigned r = (x + 0x7fffu + ((x >> 16) & 1u)) >> 16;   // RNE
    return (u16)r;
}
__device__ __forceinline__ float fast_rcp(float x) {
    return __builtin_amdgcn_rcpf(x);     // v_rcp_f32, ~1 ulp, fine pre-bf16
}
// HW packed f32->bf16 (RNE), 1 instruction for 2 values.
__device__ __forceinline__ unsigned cvt_pk_bf16(float a, float b) {
    unsigned r;
    asm("v_cvt_pk_bf16_f32 %0, %1, %2" : "=v"(r) : "v"(a), "v"(b));
    return r;
}

__device__ __forceinline__ void async_copy16(const u16* g, u16* l) {
    __builtin_amdgcn_global_load_lds(
        (const __attribute__((address_space(1))) unsigned int*)(g),
        (__attribute__((address_space(3))) unsigned int*)(l), 16, 0, 0);
}

// ---------------------------------------------------------------------------
// fp32 -> bf16 conversion, 4 elems/thread. n must be a multiple of 1024.
__global__ __launch_bounds__(256) void cvt_k(const float* __restrict__ s,
                                             u16* __restrict__ d, int n) {
    int i = (blockIdx.x * 256 + threadIdx.x) * 4;
    if (i >= n) return;
    f32x4 v = *(const f32x4*)(s + i);
    us4 o;
#pragma unroll
    for (int k = 0; k < 4; k++) o[k] = f2b(v[k]);
    *(us4*)(d + i) = o;
}

// ---------------------------------------------------------------------------
// RMSNorm from fp32 input: one block per token, D=1024, 256 threads x 4 contig.
// Optional cp: raw fp32 copy-out (folds z_before). Optional cb: raw bf16
// copy-out (folds the conn->bf16 cvt into the conn RMSNorm pass).
__global__ __launch_bounds__(256) void rmsf_k(const float* __restrict__ x,
                                              const float* __restrict__ w,
                                              u16* __restrict__ y,
                                              float* __restrict__ cp,
                                              u16* __restrict__ cb, int D) {
    int n = blockIdx.x;
    const float* xr = x + (size_t)n * D;
    int i0 = threadIdx.x << 2;
    f32x4 v = *(const f32x4*)(xr + i0);
    if (cp) *(f32x4*)(cp + (size_t)n * D + i0) = v;
    if (cb) {
        us4 o2;
#pragma unroll
        for (int k = 0; k < 4; k++) o2[k] = f2b(v[k]);
        *(us4*)(cb + (size_t)n * D + i0) = o2;
    }
    float s = v[0] * v[0] + v[1] * v[1] + v[2] * v[2] + v[3] * v[3];
#pragma unroll
    for (int m = 32; m >= 1; m >>= 1) s += __shfl_xor(s, m, 64);
    __shared__ float red[4];
    if ((threadIdx.x & 63) == 0) red[threadIdx.x >> 6] = s;
    __syncthreads();
    float tot = red[0] + red[1] + red[2] + red[3];
    float scale = rsqrtf(tot / (float)D + 1e-6f);
    f32x4 wv = *(const f32x4*)(w + i0);
    us4 o;
#pragma unroll
    for (int k = 0; k < 4; k++) o[k] = f2b(v[k] * scale * wv[k]);
    *(us4*)(y + (size_t)n * D + i0) = o;
}

// RMSNorm from bf16 (internal) input.
__global__ __launch_bounds__(256) void rmsb_k(const u16* __restrict__ x,
                                              const float* __restrict__ w,
                                              u16* __restrict__ y, int D) {
    int n = blockIdx.x;
    const u16* xr = x + (size_t)n * D;
    int i0 = threadIdx.x << 2;
    us4 xv = *(const us4*)(xr + i0);
    float v[4]; float s = 0.f;
#pragma unroll
    for (int k = 0; k < 4; k++) { v[k] = b2f(xv[k]); s += v[k] * v[k]; }
#pragma unroll
    for (int m = 32; m >= 1; m >>= 1) s += __shfl_xor(s, m, 64);
    __shared__ float red[4];
    if ((threadIdx.x & 63) == 0) red[threadIdx.x >> 6] = s;
    __syncthreads();
    float tot = red[0] + red[1] + red[2] + red[3];
    float scale = rsqrtf(tot / (float)D + 1e-6f);
    f32x4 wv = *(const f32x4*)(w + i0);
    us4 o;
#pragma unroll
    for (int k = 0; k < 4; k++) o[k] = f2b(v[k] * scale * wv[k]);
    *(us4*)(y + (size_t)n * D + i0) = o;
}

// ---------------------------------------------------------------------------
// Tiled NT GEMM: C[n,o] = epi(act(sum_k A[n,k]*W[o,k] + bias[o])).
// BM=128 x BN(128|64) tile (R6-proven geometry: tile size dominates occupancy
// — 64x64 regressed 10% in R7 despite 4 blocks/CU), BK=64, 4 waves (2x2),
// global_load_lds staging with XOR-swizzled (8-group) source addressing, LDS
// double-buffer, ONE barrier per 64-wide K-step, bijective XCD block swizzle.
// A-operand is a virtual concat of NSEG segments (native row stride 1024).
// act: 0=none 1=silu 2=tanh.
// mode (epilogue): 0 = C[idx]=bf16(v)
//   1 = per-head V-transpose: VT[((b*16+h)*64+d)*2048+tok]
//   2 = dz:   C[idx] = bf16(sc[0] * (b2f(Eb[idx]) + v))       (g_w2)
//   3 = z1:   C[idx] = bf16(Ef[idx] + b2f(Eb[idx]) + v)       (o_w)
//   4 = conn: Cf[idx] = Ef[idx] + v                           (cu_w2)
//   5 = z2:   Cf[idx] = b2f(Eb[idx]) + v                      (m_w2)
template <int BM, int BN, int NSEG>
__global__ __launch_bounds__(256) void gemm_t(const u16* __restrict__ A0,
                                              const u16* __restrict__ A1,
                                              const u16* __restrict__ A2,
                                              const u16* __restrict__ W,
                                              const float* __restrict__ bias,
                                              u16* __restrict__ C,
                                              const u16* __restrict__ Eb,
                                              const float* __restrict__ Ef,
                                              const float* __restrict__ sc,
                                              float* __restrict__ Cf,
                                              int K, int O, int act, int mode) {
    constexpr int WM = BM / 2, WN = BN / 2;      // wave tile
    constexpr int NI = WM / 16, NJ = WN / 16;    // fragment repeats
    __shared__ u16 Asm[2][BM * 64];
    __shared__ u16 Bsm[2][BN * 64];

    const int tid = threadIdx.x;
    const int wid = tid >> 6, lane = tid & 63;
    const int l15 = lane & 15, quad = lane >> 4;
    const int lsw = l15 & 7;

    // XCD-aware bijective swizzle (requires nwg % 8 == 0, true for all shapes).
    const int nwg = gridDim.x * gridDim.y;
    int id = blockIdx.y * gridDim.x + blockIdx.x;
    id = (id & 7) * (nwg >> 3) + (id >> 3);
    const int bx = id % gridDim.x, by = id / gridDim.x;

    const int row0 = by * BM, col0 = bx * BN;
    const int wm = (wid >> 1) * WM, wn = (wid & 1) * WN;

    // Staging: slot s: row r=s>>3, group g=s&7; LDS[r][g] holds source group
    // g^(r&7) (linear dest, pre-swizzled per-lane source). Each call-line of
    // 256 threads covers 32 rows x 64 cols.
    const int rb = tid >> 3;                       // 0..31
    const int gg = ((tid & 7) ^ (rb & 7)) << 3;    // source col offset, elems
    const int sA = (NSEG == 1) ? K : 1024;         // A row stride
    const size_t aoff = (size_t)(row0 + rb) * sA + gg;
    const size_t boff = (size_t)(col0 + rb) * K + gg;
    const int ldsb = wid << 9;                     // wave base within call-line

    f32x4 acc[NI][NJ];
#pragma unroll
    for (int i = 0; i < NI; i++)
#pragma unroll
        for (int j = 0; j < NJ; j++) acc[i][j] = (f32x4){0.f, 0.f, 0.f, 0.f};

    auto stage = [&](int buf, int kof) {
        const u16* Ab; int kcol;
        if constexpr (NSEG == 1) { Ab = A0; kcol = kof; }
        else {
            int seg = kof >> 10;                   // BK=64 never crosses a seg
            Ab = (seg == 0) ? A0 : ((NSEG == 3 && seg == 2) ? A2 : A1);
            kcol = kof & 1023;
        }
        const u16* as = Ab + aoff + kcol;
        const u16* bs = W + boff + kof;
#pragma unroll
        for (int i = 0; i < BM / 32; i++)
            async_copy16(as + (size_t)(32 * i) * sA, &Asm[buf][(i << 11) + ldsb]);
#pragma unroll
        for (int i = 0; i < BN / 32; i++)
            async_copy16(bs + (size_t)(32 * i) * K, &Bsm[buf][(i << 11) + ldsb]);
    };

    const int nk = K >> 6;
    stage(0, 0);
    __syncthreads();
    for (int kk = 0; kk < nk; kk++) {
        int cur = kk & 1;
        if (kk + 1 < nk) stage(1 - cur, (kk + 1) << 6);
        const u16* Ab = Asm[cur];
        const u16* Bb = Bsm[cur];
#pragma unroll
        for (int h = 0; h < 2; h++) {
            const int gq = (((h << 2) + quad) ^ lsw) << 3;
            short8 af[NI], bf[NJ];
#pragma unroll
            for (int i = 0; i < NI; i++)
                af[i] = *(const short8*)&Ab[(wm + i * 16 + l15) * 64 + gq];
#pragma unroll
            for (int j = 0; j < NJ; j++)
                bf[j] = *(const short8*)&Bb[(wn + j * 16 + l15) * 64 + gq];
#pragma unroll
            for (int i = 0; i < NI; i++)
#pragma unroll
                for (int j = 0; j < NJ; j++)
                    acc[i][j] = __builtin_amdgcn_mfma_f32_16x16x32_bf16(af[i], bf[j], acc[i][j], 0, 0, 0);
        }
        __syncthreads();
    }

    if (mode == 1) {
        // V-transpose epilogue: 4 consecutive toks -> one 8B store VT[bh][d][tok].
#pragma unroll
        for (int j = 0; j < NJ; j++) {
            int col = col0 + wn + j * 16 + l15;     // h*64 + d
            int h = col >> 6, d = col & 63;
#pragma unroll
            for (int i = 0; i < NI; i++) {
                int rowb = row0 + wm + i * 16 + (quad << 2);
                int bb_ = rowb >> 11;               // batch
                int tok = rowb & 2047;
                u32x2 pk2;
                pk2[0] = cvt_pk_bf16(acc[i][j][0], acc[i][j][1]);
                pk2[1] = cvt_pk_bf16(acc[i][j][2], acc[i][j][3]);
                *(u32x2*)&C[(size_t)(((bb_ << 4) + h) * 64 + d) * 2048 + tok] = pk2;
            }
        }
    } else {
        float dtv = (mode == 2) ? sc[0] : 0.f;
#pragma unroll
        for (int j = 0; j < NJ; j++) {
            int col = col0 + wn + j * 16 + l15;
            float bb = bias ? bias[col] : 0.f;
#pragma unroll
            for (int i = 0; i < NI; i++) {
                int rowb = row0 + wm + i * 16 + (quad << 2);
#pragma unroll
                for (int g = 0; g < 4; g++) {
                    float v = acc[i][j][g] + bb;
                    if (act == 1) {                      // silu
                        v = v * fast_rcp(1.f + __expf(-v));
                    } else if (act == 2) {               // tanh = 1 - 2/(e^2x+1)
                        float t = __expf(v * 2.f);
                        v = 1.f - 2.f * fast_rcp(1.f + t);
                    }
                    size_t idx = (size_t)(rowb + g) * O + col;
                    if (mode == 0)      C[idx] = f2b(v);
                    else if (mode == 2) C[idx] = f2b(dtv * (b2f(Eb[idx]) + v));
                    else if (mode == 3) C[idx] = f2b(Ef[idx] + b2f(Eb[idx]) + v);
                    else if (mode == 4) Cf[idx] = Ef[idx] + v;
                    else                Cf[idx] = b2f(Eb[idx]) + v;
                }
            }
        }
    }
}

// ---------------------------------------------------------------------------
// Sigmoid attention v6: LDS-staged + XCD-swizzled blocks (proven R6 structure).
// Block = 256 thr = 4 waves = 128 queries of one (b,h); 64-key tiles, double-
// buffered, one barrier/iter. Swapped QK^T (mfma(K,Q)): lane holds 4
// consecutive keys of one q-row -> sigmoid + 2x cvt_pk + ONE ds_write_b64.
__global__ __launch_bounds__(256) void attn_k(const u16* __restrict__ QK,
                                              const u16* __restrict__ VT,
                                              const float* __restrict__ temp_p,
                                              u16* __restrict__ Oa) {
    const int L = 2048, D = 1024, SQ = 2048;
    __shared__ u16 Ks[2][64 * 64];
    __shared__ u16 Vs[2][64 * 64];
    __shared__ u16 plds[4][16 * 72];

    const int tid = threadIdx.x;
    const int w = tid >> 6, lane = tid & 63;
    const int l15 = lane & 15, quad = lane >> 4;
    int id = blockIdx.x;
    id = (id & 7) * 64 + (id >> 3);           // XCD swizzle: 4 bh per XCD
    const int bh = id >> 4;                   // 16 blocks per (b,h)
    const int qb0 = (id & 15) << 7;           // 128 queries per block
    const int b = bh >> 4, h = bh & 15;
    const float nsc2 = -0.125f * temp_p[0] * 1.44269504f;  // fold log2(e)

    // Q fragments: 2 q-tiles x 2 dim-halves (k=32 each).
    short8 aq[2][2];
#pragma unroll
    for (int qt = 0; qt < 2; qt++) {
        size_t row = (size_t)(b * L + qb0 + w * 32 + qt * 16 + l15) * SQ + h * 64;
#pragma unroll
        for (int hf = 0; hf < 2; hf++)
            aq[qt][hf] = *(const short8*)(QK + row + hf * 32 + quad * 8);
    }

    const u16* Kbase = QK + 1024 + (size_t)(b * L) * SQ + h * 64;
    const u16* VTb   = VT + (size_t)bh * 64 * L;

    // Staging: slot i (0..511): row r=i>>3, group gs=i&7, src group gs^(r&7).
    const int i0 = tid, i1 = tid + 256;
    const int r0 = i0 >> 3, g0 = (i0 & 7) ^ (r0 & 7);
    const int r1 = i1 >> 3, g1 = (i1 & 7) ^ (r1 & 7);
    const u16* kS0 = Kbase + (size_t)r0 * SQ + g0 * 8;
    const u16* kS1 = Kbase + (size_t)r1 * SQ + g1 * 8;
    const u16* vS0 = VTb + (size_t)r0 * L + g0 * 8;
    const u16* vS1 = VTb + (size_t)r1 * L + g1 * 8;

    auto stage = [&](int buf, int mc) {
        async_copy16(kS0 + (size_t)mc * SQ, &Ks[buf][w << 9]);
        async_copy16(kS1 + (size_t)mc * SQ, &Ks[buf][2048 + (w << 9)]);
        async_copy16(vS0 + mc, &Vs[buf][w << 9]);
        async_copy16(vS1 + mc, &Vs[buf][2048 + (w << 9)]);
    };

    f32x4 acc[2][4];
#pragma unroll
    for (int i = 0; i < 2; i++)
#pragma unroll
        for (int j = 0; j < 4; j++) acc[i][j] = (f32x4){0.f, 0.f, 0.f, 0.f};
    float rs[2] = {0.f, 0.f};
    u16* P = plds[w];
    const int lsw = l15 & 7;   // read-side swizzle key

    stage(0, 0);
    __syncthreads();
    for (int it = 0; it < 32; it++) {
        int cur = it & 1;
        if (it < 31) stage(1 - cur, (it + 1) << 6);
        const u16* Kt = Ks[cur];
        const u16* Vt = Vs[cur];
#pragma unroll
        for (int qt = 0; qt < 2; qt++) {
#pragma unroll
            for (int ks = 0; ks < 4; ks++) {
                f32x4 s = (f32x4){0.f, 0.f, 0.f, 0.f};
#pragma unroll
                for (int hf = 0; hf < 2; hf++) {
                    int slot = ((ks * 16 + l15) * 8 + ((hf * 4 + quad) ^ lsw)) * 8;
                    short8 bk = *(const short8*)&Kt[slot];
                    // swapped: A=K (row=key), B=Q (col=q)
                    s = __builtin_amdgcn_mfma_f32_16x16x32_bf16(bk, aq[qt][hf], s, 0, 0, 0);
                }
                float p0 = fast_rcp(1.f + __builtin_amdgcn_exp2f(s[0] * nsc2));
                float p1 = fast_rcp(1.f + __builtin_amdgcn_exp2f(s[1] * nsc2));
                float p2 = fast_rcp(1.f + __builtin_amdgcn_exp2f(s[2] * nsc2));
                float p3 = fast_rcp(1.f + __builtin_amdgcn_exp2f(s[3] * nsc2));
                rs[qt] += (p0 + p1) + (p2 + p3);
                u32x2 pk2;
                pk2[0] = cvt_pk_bf16(p0, p1);
                pk2[1] = cvt_pk_bf16(p2, p3);
                // P[q = l15][key = ks*16 + quad*4 .. +3], 8B aligned store
                *(u32x2*)&P[l15 * 72 + ks * 16 + (quad << 2)] = pk2;
            }
#pragma unroll
            for (int kh = 0; kh < 2; kh++) {
                short8 ap = *(const short8*)&P[l15 * 72 + kh * 32 + quad * 8];
#pragma unroll
                for (int dt = 0; dt < 4; dt++) {
                    int slot = ((dt * 16 + l15) * 8 + ((kh * 4 + quad) ^ lsw)) * 8;
                    short8 bv = *(const short8*)&Vt[slot];
                    acc[qt][dt] = __builtin_amdgcn_mfma_f32_16x16x32_bf16(ap, bv, acc[qt][dt], 0, 0, 0);
                }
            }
        }
        __syncthreads();
    }

    // rs: per-lane partial over its quad's keys; reduce across quad dimension.
#pragma unroll
    for (int qt = 0; qt < 2; qt++) {
        rs[qt] += __shfl_xor(rs[qt], 16, 64);
        rs[qt] += __shfl_xor(rs[qt], 32, 64);
    }

#pragma unroll
    for (int qt = 0; qt < 2; qt++) {
        u16* orow = Oa + (size_t)(b * L + qb0 + w * 32 + qt * 16) * D + h * 64;
#pragma unroll
        for (int g = 0; g < 4; g++) {
            int row = quad * 4 + g;
            float denom = __shfl(rs[qt], row, 64);   // lane 'row' holds q=row
            float rd = fast_rcp(fmaxf(denom, 1.0f));
#pragma unroll
            for (int dt = 0; dt < 4; dt++)
                orow[(size_t)row * D + dt * 16 + l15] = f2b(acc[qt][dt][g] * rd);
        }
    }
}

// ---------------------------------------------------------------------------
extern "C" void kernel_launch(void* const* d_in, const int* in_sizes, int n_in,
                              void* d_out, int out_size, void* d_ws, size_t ws_size,
                              hipStream_t stream) {
    const int B = 2, L = 2048, D = 1024, H = 16, N = B * L;
    const float* z      = (const float*)d_in[0];
    const float* conn   = (const float*)d_in[1];
    const float* w_z    = (const float*)d_in[2];
    const float* w_c    = (const float*)d_in[3];
    const float* w_mlp  = (const float*)d_in[4];
    const float* f_w1   = (const float*)d_in[5];
    const float* f_b1   = (const float*)d_in[6];
    const float* f_w2   = (const float*)d_in[7];
    const float* f_b2   = (const float*)d_in[8];
    const float* g_w1   = (const float*)d_in[9];
    const float* g_b1   = (const float*)d_in[10];
    const float* g_w2   = (const float*)d_in[11];
    const float* g_b2   = (const float*)d_in[12];
    const float* dt_p   = (const float*)d_in[13];
    const float* q_w    = (const float*)d_in[14];
    const float* k_w    = (const float*)d_in[15];
    const float* v_w    = (const float*)d_in[16];
    const float* o_w    = (const float*)d_in[17];
    const float* temp_p = (const float*)d_in[18];
    const float* cu_w1  = (const float*)d_in[19];
    const float* cu_b1  = (const float*)d_in[20];
    const float* cu_w2  = (const float*)d_in[21];
    const float* cu_b2  = (const float*)d_in[22];
    const float* m_w1   = (const float*)d_in[23];
    const float* m_b1   = (const float*)d_in[24];
    const float* m_w2   = (const float*)d_in[25];
    const float* m_b2   = (const float*)d_in[26];

    float* out = (float*)d_out;
    u16* ws  = (u16*)d_ws;
    const size_t U = (size_t)N * D;   // 4M elems

    // Activation slots (bf16), liveness-packed:
    // slot0: zn -> z1n         slot1: cn -> attnb -> mh[0]
    // slot2: h1[0] -> QK[0] -> cu_h[0] -> mh[1]
    // slot3: h1[1] -> QK[1] -> cu_h[1] -> mh[2]
    // slot4: dzl -> VT -> mh[3]
    // slot5: gh -> z1          slot6: dz          slot7: connb
    u16* zn    = ws + 0 * U;
    u16* cn    = ws + 1 * U;
    u16* h1    = ws + 2 * U;   // 2 units
    u16* dzl   = ws + 4 * U;
    u16* gh    = ws + 5 * U;
    u16* dz    = ws + 6 * U;
    u16* connb = ws + 7 * U;
    u16* QK    = ws + 2 * U;   // 2 units (h1 dead): [N][2048], Q|K
    u16* VT    = ws + 4 * U;   // dzl dead after g_w2 epi; VT[bh][64][L]
    u16* attnb = ws + 1 * U;   // cn dead after QK gemm
    u16* z1    = ws + 5 * U;   // gh dead after g_w2
    u16* cu_h  = ws + 2 * U;   // 2 units, QK dead after attn
    u16* z1n   = ws + 0 * U;   // zn dead after v_w
    u16* mh    = ws + 1 * U;   // 4 units (1-4): attnb, cu_h, VT dead

    // bf16 weight copies after activation slots: 29M u16 elems.
    u16* wb = ws + 9 * U;
    u16* bf_w1  = wb + 0;                       // 2M
    u16* bf_w2  = wb + 2 * 1024 * 1024;         // 2M
    u16* bg_w1  = wb + 4 * 1024 * 1024;         // 2M
    u16* bg_w2  = wb + 6 * 1024 * 1024;         // 1M
    u16* bqk_w  = wb + 7 * 1024 * 1024;         // 4M: q_w rows then k_w rows
    u16* bv_w   = wb + 11 * 1024 * 1024;        // 1M
    u16* bo_w   = wb + 12 * 1024 * 1024;        // 1M
    u16* bcu_w1 = wb + 13 * 1024 * 1024;        // 6M
    u16* bcu_w2 = wb + 19 * 1024 * 1024;        // 2M
    u16* bm_w1  = wb + 21 * 1024 * 1024;        // 4M
    u16* bm_w2  = wb + 25 * 1024 * 1024;        // 4M

    auto cvt = [&](const float* s, u16* d, int n) {
        cvt_k<<<n / 1024, 256, 0, stream>>>(s, d, n);
    };
    cvt(f_w1, bf_w1, 2 * D * D);   cvt(f_w2, bf_w2, 2 * D * D);
    cvt(g_w1, bg_w1, 2 * D * D);   cvt(g_w2, bg_w2, D * D);
    cvt(q_w, bqk_w, 2 * D * D);    cvt(k_w, bqk_w + 2 * D * D, 2 * D * D);
    cvt(v_w, bv_w, D * D);         cvt(o_w, bo_w, D * D);
    cvt(cu_w1, bcu_w1, 6 * D * D); cvt(cu_w2, bcu_w2, 2 * D * D);
    cvt(m_w1, bm_w1, 4 * D * D);   cvt(m_w2, bm_w2, 4 * D * D);

    rmsf_k<<<N, 256, 0, stream>>>(z, w_z, zn, out + 2 * U, nullptr, D);  // + z_before
    rmsf_k<<<N, 256, 0, stream>>>(conn, w_c, cn, nullptr, connb, D);     // + conn bf16

    const u16* nu = nullptr;
    // dz_local = f_w2(silu(f_w1(zn)))
    gemm_t<128, 128, 1><<<dim3(16, 32), 256, 0, stream>>>(
        zn, nu, nu, bf_w1, f_b1, h1, nu, nullptr, nullptr, nullptr, D, 2 * D, 1, 0);
    gemm_t<128, 64, 1><<<dim3(16, 32), 256, 0, stream>>>(
        h1, nu, nu, bf_w2, f_b2, dzl, nu, nullptr, nullptr, nullptr, 2 * D, D, 0, 0);
    // corr path; g_w2 epilogue writes dz = dt*(dzl + corr) directly (mode 2)
    gemm_t<128, 64, 2><<<dim3(16, 32), 256, 0, stream>>>(
        cn, dzl, nu, bg_w1, g_b1, gh, nu, nullptr, nullptr, nullptr, 2 * D, D, 2, 0);
    gemm_t<128, 64, 1><<<dim3(16, 32), 256, 0, stream>>>(
        gh, nu, nu, bg_w2, g_b2, dz, dzl, nullptr, dt_p, nullptr, D, D, 0, 2);

    // attention: fused Q|K, V-transpose, sigmoid attn, o-proj (+z1 fusion)
    gemm_t<128, 128, 2><<<dim3(16, 32), 256, 0, stream>>>(
        zn, cn, nu, bqk_w, nullptr, QK, nu, nullptr, nullptr, nullptr, 2 * D, 2 * D, 0, 0);
    gemm_t<128, 64, 1><<<dim3(16, 32), 256, 0, stream>>>(
        zn, nu, nu, bv_w, nullptr, VT, nu, nullptr, nullptr, nullptr, D, D, 0, 1);
    attn_k<<<B * H * L / 128, 256, 0, stream>>>(QK, VT, temp_p, attnb);
    gemm_t<128, 64, 1><<<dim3(16, 32), 256, 0, stream>>>(       // z1 = z + dz + ctx
        attnb, nu, nu, bo_w, nullptr, z1, dz, z, nullptr, nullptr, D, D, 0, 3);

    // connection update; cu_w2 epilogue writes conn_new (fp32) directly
    gemm_t<128, 128, 3><<<dim3(16, 32), 256, 0, stream>>>(
        connb, z1, dz, bcu_w1, cu_b1, cu_h, nu, nullptr, nullptr, nullptr, 3 * D, 2 * D, 1, 0);
    gemm_t<128, 64, 1><<<dim3(16, 32), 256, 0, stream>>>(
        cu_h, nu, nu, bcu_w2, cu_b2, (u16*)nullptr, nu, conn, nullptr, out + U, 2 * D, D, 0, 4);

    // MLP block; m_w2 epilogue writes z2 (fp32) directly
    rmsb_k<<<N, 256, 0, stream>>>(z1, w_mlp, z1n, D);
    gemm_t<128, 128, 1><<<dim3(32, 32), 256, 0, stream>>>(
        z1n, nu, nu, bm_w1, m_b1, mh, nu, nullptr, nullptr, nullptr, D, 4 * D, 1, 0);
    gemm_t<128, 64, 1><<<dim3(16, 32), 256, 0, stream>>>(
        mh, nu, nu, bm_w2, m_b2, (u16*)nullptr, z1, nullptr, nullptr, out, 4 * D, D, 0, 5);
}

// Round 9
// 728.385 us; speedup vs baseline: 1.0499x; 1.0181x over previous
//
#include <hip/hip_runtime.h>

// CovariantEvolutionBlock on MI355X (gfx950).
// I/O is float32 (bf16-grid values); internal compute bf16 MFMA + fp32 accum.
// B=2, L=2048, D=1024, H=16, HD=64, N=B*L=4096 tokens.

typedef unsigned short u16;
typedef __attribute__((ext_vector_type(8))) short short8;
typedef __attribute__((ext_vector_type(8))) unsigned short us8;
typedef __attribute__((ext_vector_type(4))) float f32x4;
typedef __attribute__((ext_vector_type(4))) unsigned short us4;
typedef __attribute__((ext_vector_type(2))) unsigned int u32x2;

__device__ __forceinline__ float b2f(u16 u) {
    union { unsigned u; float f; } c; c.u = ((unsigned)u) << 16; return c.f;
}
__device__ __forceinline__ u16 f2b(float f) {
    union { float f; unsigned u; } c; c.f = f;
    unsigned x = c.u;
    unsigned r = (x + 0x7fffu + ((x >> 16) & 1u)) >> 16;   // RNE
    return (u16)r;
}
__device__ __forceinline__ float fast_rcp(float x) {
    return __builtin_amdgcn_rcpf(x);     // v_rcp_f32, ~1 ulp, fine pre-bf16
}
// HW packed f32->bf16 (RNE), 1 instruction for 2 values.
__device__ __forceinline__ unsigned cvt_pk_bf16(float a, float b) {
    unsigned r;
    asm("v_cvt_pk_bf16_f32 %0, %1, %2" : "=v"(r) : "v"(a), "v"(b));
    return r;
}

__device__ __forceinline__ void async_copy16(const u16* g, u16* l) {
    __builtin_amdgcn_global_load_lds(
        (const __attribute__((address_space(1))) unsigned int*)(g),
        (__attribute__((address_space(3))) unsigned int*)(l), 16, 0, 0);
}

// ---------------------------------------------------------------------------
// Fused fp32->bf16 conversion of ALL weight matrices in one dispatch.
// Destinations are contiguous in wb at cumulative offsets cum[] (1024-elem
// blocks); one launch replaces 12 separate cvt_k dispatches.
struct CvtArgs {
    const float* s[12];
    int cum[13];          // cumulative block counts (1 block = 1024 elems)
};
__global__ __launch_bounds__(256) void cvtall_k(CvtArgs a, u16* __restrict__ dst) {
    int blk = blockIdx.x;
    int seg = 0;
    while (blk >= a.cum[seg + 1]) seg++;          // <=12 scalar iters
    int local = blk - a.cum[seg];
    const float* s = a.s[seg] + (size_t)local * 1024;
    u16* d = dst + (size_t)blk * 1024;
    int i = threadIdx.x << 2;
    f32x4 v = *(const f32x4*)(s + i);
    us4 o;
#pragma unroll
    for (int k = 0; k < 4; k++) o[k] = f2b(v[k]);
    *(us4*)(d + i) = o;
}

// ---------------------------------------------------------------------------
// RMSNorm from fp32 input: one block per token, D=1024, 256 threads x 4 contig.
// Optional cp: raw fp32 copy-out (folds z_before). Optional cb: raw bf16
// copy-out (folds the conn->bf16 cvt into the conn RMSNorm pass).
__global__ __launch_bounds__(256) void rmsf_k(const float* __restrict__ x,
                                              const float* __restrict__ w,
                                              u16* __restrict__ y,
                                              float* __restrict__ cp,
                                              u16* __restrict__ cb, int D) {
    int n = blockIdx.x;
    const float* xr = x + (size_t)n * D;
    int i0 = threadIdx.x << 2;
    f32x4 v = *(const f32x4*)(xr + i0);
    if (cp) *(f32x4*)(cp + (size_t)n * D + i0) = v;
    if (cb) {
        us4 o2;
#pragma unroll
        for (int k = 0; k < 4; k++) o2[k] = f2b(v[k]);
        *(us4*)(cb + (size_t)n * D + i0) = o2;
    }
    float s = v[0] * v[0] + v[1] * v[1] + v[2] * v[2] + v[3] * v[3];
#pragma unroll
    for (int m = 32; m >= 1; m >>= 1) s += __shfl_xor(s, m, 64);
    __shared__ float red[4];
    if ((threadIdx.x & 63) == 0) red[threadIdx.x >> 6] = s;
    __syncthreads();
    float tot = red[0] + red[1] + red[2] + red[3];
    float scale = rsqrtf(tot / (float)D + 1e-6f);
    f32x4 wv = *(const f32x4*)(w + i0);
    us4 o;
#pragma unroll
    for (int k = 0; k < 4; k++) o[k] = f2b(v[k] * scale * wv[k]);
    *(us4*)(y + (size_t)n * D + i0) = o;
}

// RMSNorm from bf16 (internal) input.
__global__ __launch_bounds__(256) void rmsb_k(const u16* __restrict__ x,
                                              const float* __restrict__ w,
                                              u16* __restrict__ y, int D) {
    int n = blockIdx.x;
    const u16* xr = x + (size_t)n * D;
    int i0 = threadIdx.x << 2;
    us4 xv = *(const us4*)(xr + i0);
    float v[4]; float s = 0.f;
#pragma unroll
    for (int k = 0; k < 4; k++) { v[k] = b2f(xv[k]); s += v[k] * v[k]; }
#pragma unroll
    for (int m = 32; m >= 1; m >>= 1) s += __shfl_xor(s, m, 64);
    __shared__ float red[4];
    if ((threadIdx.x & 63) == 0) red[threadIdx.x >> 6] = s;
    __syncthreads();
    float tot = red[0] + red[1] + red[2] + red[3];
    float scale = rsqrtf(tot / (float)D + 1e-6f);
    f32x4 wv = *(const f32x4*)(w + i0);
    us4 o;
#pragma unroll
    for (int k = 0; k < 4; k++) o[k] = f2b(v[k] * scale * wv[k]);
    *(us4*)(y + (size_t)n * D + i0) = o;
}

// ---------------------------------------------------------------------------
// Tiled NT GEMM: C[n,o] = epi(act(sum_k A[n,k]*W[o,k] + bias[o])).
// BM=128 x BN(128|64) tile (R6-proven geometry: tile size dominates occupancy
// — 64x64 regressed 10% in R7 despite 4 blocks/CU), BK=64, 4 waves (2x2),
// global_load_lds staging with XOR-swizzled (8-group) source addressing, LDS
// double-buffer, ONE barrier per 64-wide K-step, bijective XCD block swizzle.
// A-operand is a virtual concat of NSEG segments (native row stride 1024).
// act: 0=none 1=silu 2=tanh.
// mode (epilogue): 0 = C[idx]=bf16(v)
//   1 = per-head V-transpose: VT[((b*16+h)*64+d)*2048+tok]
//   2 = dz:   C[idx] = bf16(sc[0] * (b2f(Eb[idx]) + v))       (g_w2)
//   3 = z1:   C[idx] = bf16(Ef[idx] + b2f(Eb[idx]) + v)       (o_w)
//   4 = conn: Cf[idx] = Ef[idx] + v                           (cu_w2)
//   5 = z2:   Cf[idx] = b2f(Eb[idx]) + v                      (m_w2)
template <int BM, int BN, int NSEG>
__global__ __launch_bounds__(256) void gemm_t(const u16* __restrict__ A0,
                                              const u16* __restrict__ A1,
                                              const u16* __restrict__ A2,
                                              const u16* __restrict__ W,
                                              const float* __restrict__ bias,
                                              u16* __restrict__ C,
                                              const u16* __restrict__ Eb,
                                              const float* __restrict__ Ef,
                                              const float* __restrict__ sc,
                                              float* __restrict__ Cf,
                                              int K, int O, int act, int mode) {
    constexpr int WM = BM / 2, WN = BN / 2;      // wave tile
    constexpr int NI = WM / 16, NJ = WN / 16;    // fragment repeats
    __shared__ u16 Asm[2][BM * 64];
    __shared__ u16 Bsm[2][BN * 64];

    const int tid = threadIdx.x;
    const int wid = tid >> 6, lane = tid & 63;
    const int l15 = lane & 15, quad = lane >> 4;
    const int lsw = l15 & 7;

    // XCD-aware bijective swizzle (requires nwg % 8 == 0, true for all shapes).
    const int nwg = gridDim.x * gridDim.y;
    int id = blockIdx.y * gridDim.x + blockIdx.x;
    id = (id & 7) * (nwg >> 3) + (id >> 3);
    const int bx = id % gridDim.x, by = id / gridDim.x;

    const int row0 = by * BM, col0 = bx * BN;
    const int wm = (wid >> 1) * WM, wn = (wid & 1) * WN;

    // Staging: slot s: row r=s>>3, group g=s&7; LDS[r][g] holds source group
    // g^(r&7) (linear dest, pre-swizzled per-lane source). Each call-line of
    // 256 threads covers 32 rows x 64 cols.
    const int rb = tid >> 3;                       // 0..31
    const int gg = ((tid & 7) ^ (rb & 7)) << 3;    // source col offset, elems
    const int sA = (NSEG == 1) ? K : 1024;         // A row stride
    const size_t aoff = (size_t)(row0 + rb) * sA + gg;
    const size_t boff = (size_t)(col0 + rb) * K + gg;
    const int ldsb = wid << 9;                     // wave base within call-line

    f32x4 acc[NI][NJ];
#pragma unroll
    for (int i = 0; i < NI; i++)
#pragma unroll
        for (int j = 0; j < NJ; j++) acc[i][j] = (f32x4){0.f, 0.f, 0.f, 0.f};

    auto stage = [&](int buf, int kof) {
        const u16* Ab; int kcol;
        if constexpr (NSEG == 1) { Ab = A0; kcol = kof; }
        else {
            int seg = kof >> 10;                   // BK=64 never crosses a seg
            Ab = (seg == 0) ? A0 : ((NSEG == 3 && seg == 2) ? A2 : A1);
            kcol = kof & 1023;
        }
        const u16* as = Ab + aoff + kcol;
        const u16* bs = W + boff + kof;
#pragma unroll
        for (int i = 0; i < BM / 32; i++)
            async_copy16(as + (size_t)(32 * i) * sA, &Asm[buf][(i << 11) + ldsb]);
#pragma unroll
        for (int i = 0; i < BN / 32; i++)
            async_copy16(bs + (size_t)(32 * i) * K, &Bsm[buf][(i << 11) + ldsb]);
    };

    const int nk = K >> 6;
    stage(0, 0);
    __syncthreads();
    for (int kk = 0; kk < nk; kk++) {
        int cur = kk & 1;
        if (kk + 1 < nk) stage(1 - cur, (kk + 1) << 6);
        const u16* Ab = Asm[cur];
        const u16* Bb = Bsm[cur];
#pragma unroll
        for (int h = 0; h < 2; h++) {
            const int gq = (((h << 2) + quad) ^ lsw) << 3;
            short8 af[NI], bf[NJ];
#pragma unroll
            for (int i = 0; i < NI; i++)
                af[i] = *(const short8*)&Ab[(wm + i * 16 + l15) * 64 + gq];
#pragma unroll
            for (int j = 0; j < NJ; j++)
                bf[j] = *(const short8*)&Bb[(wn + j * 16 + l15) * 64 + gq];
#pragma unroll
            for (int i = 0; i < NI; i++)
#pragma unroll
                for (int j = 0; j < NJ; j++)
                    acc[i][j] = __builtin_amdgcn_mfma_f32_16x16x32_bf16(af[i], bf[j], acc[i][j], 0, 0, 0);
        }
        __syncthreads();
    }

    if (mode == 1) {
        // V-transpose epilogue: 4 consecutive toks -> one 8B store VT[bh][d][tok].
#pragma unroll
        for (int j = 0; j < NJ; j++) {
            int col = col0 + wn + j * 16 + l15;     // h*64 + d
            int h = col >> 6, d = col & 63;
#pragma unroll
            for (int i = 0; i < NI; i++) {
                int rowb = row0 + wm + i * 16 + (quad << 2);
                int bb_ = rowb >> 11;               // batch
                int tok = rowb & 2047;
                u32x2 pk2;
                pk2[0] = cvt_pk_bf16(acc[i][j][0], acc[i][j][1]);
                pk2[1] = cvt_pk_bf16(acc[i][j][2], acc[i][j][3]);
                *(u32x2*)&C[(size_t)(((bb_ << 4) + h) * 64 + d) * 2048 + tok] = pk2;
            }
        }
    } else {
        float dtv = (mode == 2) ? sc[0] : 0.f;
#pragma unroll
        for (int j = 0; j < NJ; j++) {
            int col = col0 + wn + j * 16 + l15;
            float bb = bias ? bias[col] : 0.f;
#pragma unroll
            for (int i = 0; i < NI; i++) {
                int rowb = row0 + wm + i * 16 + (quad << 2);
#pragma unroll
                for (int g = 0; g < 4; g++) {
                    float v = acc[i][j][g] + bb;
                    if (act == 1) {                      // silu
                        v = v * fast_rcp(1.f + __expf(-v));
                    } else if (act == 2) {               // tanh = 1 - 2/(e^2x+1)
                        float t = __expf(v * 2.f);
                        v = 1.f - 2.f * fast_rcp(1.f + t);
                    }
                    size_t idx = (size_t)(rowb + g) * O + col;
                    if (mode == 0)      C[idx] = f2b(v);
                    else if (mode == 2) C[idx] = f2b(dtv * (b2f(Eb[idx]) + v));
                    else if (mode == 3) C[idx] = f2b(Ef[idx] + b2f(Eb[idx]) + v);
                    else if (mode == 4) Cf[idx] = Ef[idx] + v;
                    else                Cf[idx] = b2f(Eb[idx]) + v;
                }
            }
        }
    }
}

// ---------------------------------------------------------------------------
// Sigmoid attention v7: LDS-staged + XCD-swizzled (R6 structure) with 64
// queries/block. Grid 512 pinned occupancy at 2 blocks/CU (grid-limited, not
// resource-limited: LDS 41KB allows 3). Halving the per-block query tile
// doubles the grid to 1024 -> 3 blocks/CU = 12 waves/CU, covering the ~39%
// latency-idle seen at 2/CU. Extra K/V staging repeats are L2-resident.
// Each wave owns 16 queries; 64-key tiles, double-buffered, 1 barrier/iter.
// Swapped QK^T (mfma(K,Q)): lane holds 4 consecutive keys of one q-row ->
// sigmoid + 2x cvt_pk + ONE ds_write_b64.
__global__ __launch_bounds__(256) void attn_k(const u16* __restrict__ QK,
                                              const u16* __restrict__ VT,
                                              const float* __restrict__ temp_p,
                                              u16* __restrict__ Oa) {
    const int L = 2048, D = 1024, SQ = 2048;
    __shared__ u16 Ks[2][64 * 64];
    __shared__ u16 Vs[2][64 * 64];
    __shared__ u16 plds[4][16 * 72];

    const int tid = threadIdx.x;
    const int w = tid >> 6, lane = tid & 63;
    const int l15 = lane & 15, quad = lane >> 4;
    int id = blockIdx.x;
    id = (id & 7) * 128 + (id >> 3);          // XCD swizzle: 4 bh per XCD
    const int bh = id >> 5;                   // 32 blocks per (b,h)
    const int qb0 = (id & 31) << 6;           // 64 queries per block
    const int b = bh >> 4, h = bh & 15;
    const float nsc2 = -0.125f * temp_p[0] * 1.44269504f;  // fold log2(e)

    // Q fragments: one 16-q tile per wave x 2 dim-halves (k=32 each).
    short8 aq[2];
    {
        size_t row = (size_t)(b * L + qb0 + w * 16 + l15) * SQ + h * 64;
#pragma unroll
        for (int hf = 0; hf < 2; hf++)
            aq[hf] = *(const short8*)(QK + row + hf * 32 + quad * 8);
    }

    const u16* Kbase = QK + 1024 + (size_t)(b * L) * SQ + h * 64;
    const u16* VTb   = VT + (size_t)bh * 64 * L;

    // Staging: slot i (0..511): row r=i>>3, group gs=i&7, src group gs^(r&7).
    const int i0 = tid, i1 = tid + 256;
    const int r0 = i0 >> 3, g0 = (i0 & 7) ^ (r0 & 7);
    const int r1 = i1 >> 3, g1 = (i1 & 7) ^ (r1 & 7);
    const u16* kS0 = Kbase + (size_t)r0 * SQ + g0 * 8;
    const u16* kS1 = Kbase + (size_t)r1 * SQ + g1 * 8;
    const u16* vS0 = VTb + (size_t)r0 * L + g0 * 8;
    const u16* vS1 = VTb + (size_t)r1 * L + g1 * 8;

    auto stage = [&](int buf, int mc) {
        async_copy16(kS0 + (size_t)mc * SQ, &Ks[buf][w << 9]);
        async_copy16(kS1 + (size_t)mc * SQ, &Ks[buf][2048 + (w << 9)]);
        async_copy16(vS0 + mc, &Vs[buf][w << 9]);
        async_copy16(vS1 + mc, &Vs[buf][2048 + (w << 9)]);
    };

    f32x4 acc[4];
#pragma unroll
    for (int j = 0; j < 4; j++) acc[j] = (f32x4){0.f, 0.f, 0.f, 0.f};
    float rs = 0.f;
    u16* P = plds[w];
    const int lsw = l15 & 7;   // read-side swizzle key

    stage(0, 0);
    __syncthreads();
    for (int it = 0; it < 32; it++) {
        int cur = it & 1;
        if (it < 31) stage(1 - cur, (it + 1) << 6);
        const u16* Kt = Ks[cur];
        const u16* Vt = Vs[cur];
#pragma unroll
        for (int ks = 0; ks < 4; ks++) {
            f32x4 s = (f32x4){0.f, 0.f, 0.f, 0.f};
#pragma unroll
            for (int hf = 0; hf < 2; hf++) {
                int slot = ((ks * 16 + l15) * 8 + ((hf * 4 + quad) ^ lsw)) * 8;
                short8 bk = *(const short8*)&Kt[slot];
                // swapped: A=K (row=key), B=Q (col=q)
                s = __builtin_amdgcn_mfma_f32_16x16x32_bf16(bk, aq[hf], s, 0, 0, 0);
            }
            float p0 = fast_rcp(1.f + __builtin_amdgcn_exp2f(s[0] * nsc2));
            float p1 = fast_rcp(1.f + __builtin_amdgcn_exp2f(s[1] * nsc2));
            float p2 = fast_rcp(1.f + __builtin_amdgcn_exp2f(s[2] * nsc2));
            float p3 = fast_rcp(1.f + __builtin_amdgcn_exp2f(s[3] * nsc2));
            rs += (p0 + p1) + (p2 + p3);
            u32x2 pk2;
            pk2[0] = cvt_pk_bf16(p0, p1);
            pk2[1] = cvt_pk_bf16(p2, p3);
            // P[q = l15][key = ks*16 + quad*4 .. +3], 8B aligned store
            *(u32x2*)&P[l15 * 72 + ks * 16 + (quad << 2)] = pk2;
        }
#pragma unroll
        for (int kh = 0; kh < 2; kh++) {
            short8 ap = *(const short8*)&P[l15 * 72 + kh * 32 + quad * 8];
#pragma unroll
            for (int dt = 0; dt < 4; dt++) {
                int slot = ((dt * 16 + l15) * 8 + ((kh * 4 + quad) ^ lsw)) * 8;
                short8 bv = *(const short8*)&Vt[slot];
                acc[dt] = __builtin_amdgcn_mfma_f32_16x16x32_bf16(ap, bv, acc[dt], 0, 0, 0);
            }
        }
        __syncthreads();
    }

    // rs: per-lane partial over its quad's keys; reduce across quad dimension.
    rs += __shfl_xor(rs, 16, 64);
    rs += __shfl_xor(rs, 32, 64);

    u16* orow = Oa + (size_t)(b * L + qb0 + w * 16) * D + h * 64;
#pragma unroll
    for (int g = 0; g < 4; g++) {
        int row = quad * 4 + g;
        float denom = __shfl(rs, row, 64);   // lane 'row' holds q=row
        float rd = fast_rcp(fmaxf(denom, 1.0f));
#pragma unroll
        for (int dt = 0; dt < 4; dt++)
            orow[(size_t)row * D + dt * 16 + l15] = f2b(acc[dt][g] * rd);
    }
}

// ---------------------------------------------------------------------------
extern "C" void kernel_launch(void* const* d_in, const int* in_sizes, int n_in,
                              void* d_out, int out_size, void* d_ws, size_t ws_size,
                              hipStream_t stream) {
    const int B = 2, L = 2048, D = 1024, H = 16, N = B * L;
    const float* z      = (const float*)d_in[0];
    const float* conn   = (const float*)d_in[1];
    const float* w_z    = (const float*)d_in[2];
    const float* w_c    = (const float*)d_in[3];
    const float* w_mlp  = (const float*)d_in[4];
    const float* f_w1   = (const float*)d_in[5];
    const float* f_b1   = (const float*)d_in[6];
    const float* f_w2   = (const float*)d_in[7];
    const float* f_b2   = (const float*)d_in[8];
    const float* g_w1   = (const float*)d_in[9];
    const float* g_b1   = (const float*)d_in[10];
    const float* g_w2   = (const float*)d_in[11];
    const float* g_b2   = (const float*)d_in[12];
    const float* dt_p   = (const float*)d_in[13];
    const float* q_w    = (const float*)d_in[14];
    const float* k_w    = (const float*)d_in[15];
    const float* v_w    = (const float*)d_in[16];
    const float* o_w    = (const float*)d_in[17];
    const float* temp_p = (const float*)d_in[18];
    const float* cu_w1  = (const float*)d_in[19];
    const float* cu_b1  = (const float*)d_in[20];
    const float* cu_w2  = (const float*)d_in[21];
    const float* cu_b2  = (const float*)d_in[22];
    const float* m_w1   = (const float*)d_in[23];
    const float* m_b1   = (const float*)d_in[24];
    const float* m_w2   = (const float*)d_in[25];
    const float* m_b2   = (const float*)d_in[26];

    float* out = (float*)d_out;
    u16* ws  = (u16*)d_ws;
    const size_t U = (size_t)N * D;   // 4M elems

    // Activation slots (bf16), liveness-packed:
    // slot0: zn -> z1n         slot1: cn -> attnb -> mh[0]
    // slot2: h1[0] -> QK[0] -> cu_h[0] -> mh[1]
    // slot3: h1[1] -> QK[1] -> cu_h[1] -> mh[2]
    // slot4: dzl -> VT -> mh[3]
    // slot5: gh -> z1          slot6: dz          slot7: connb
    u16* zn    = ws + 0 * U;
    u16* cn    = ws + 1 * U;
    u16* h1    = ws + 2 * U;   // 2 units
    u16* dzl   = ws + 4 * U;
    u16* gh    = ws + 5 * U;
    u16* dz    = ws + 6 * U;
    u16* connb = ws + 7 * U;
    u16* QK    = ws + 2 * U;   // 2 units (h1 dead): [N][2048], Q|K
    u16* VT    = ws + 4 * U;   // dzl dead after g_w2 epi; VT[bh][64][L]
    u16* attnb = ws + 1 * U;   // cn dead after QK gemm
    u16* z1    = ws + 5 * U;   // gh dead after g_w2
    u16* cu_h  = ws + 2 * U;   // 2 units, QK dead after attn
    u16* z1n   = ws + 0 * U;   // zn dead after v_w
    u16* mh    = ws + 1 * U;   // 4 units (1-4): attnb, cu_h, VT dead

    // bf16 weight copies after activation slots: 29M u16 elems, contiguous,
    // in cvtall order.
    u16* wb = ws + 9 * U;
    u16* bf_w1  = wb + 0;                       // 2M
    u16* bf_w2  = wb + 2 * 1024 * 1024;         // 2M
    u16* bg_w1  = wb + 4 * 1024 * 1024;         // 2M
    u16* bg_w2  = wb + 6 * 1024 * 1024;         // 1M
    u16* bqk_w  = wb + 7 * 1024 * 1024;         // 4M: q_w rows then k_w rows
    u16* bv_w   = wb + 11 * 1024 * 1024;        // 1M
    u16* bo_w   = wb + 12 * 1024 * 1024;        // 1M
    u16* bcu_w1 = wb + 13 * 1024 * 1024;        // 6M
    u16* bcu_w2 = wb + 19 * 1024 * 1024;        // 2M
    u16* bm_w1  = wb + 21 * 1024 * 1024;        // 4M
    u16* bm_w2  = wb + 25 * 1024 * 1024;        // 4M

    // One fused weight-conversion dispatch (12 segments, cumulative 1K-blocks).
    CvtArgs ca;
    ca.s[0] = f_w1;  ca.s[1] = f_w2;  ca.s[2] = g_w1;  ca.s[3] = g_w2;
    ca.s[4] = q_w;   ca.s[5] = k_w;   ca.s[6] = v_w;   ca.s[7] = o_w;
    ca.s[8] = cu_w1; ca.s[9] = cu_w2; ca.s[10] = m_w1; ca.s[11] = m_w2;
    const int segb[12] = {2048, 2048, 2048, 1024, 2048, 2048, 1024, 1024,
                          6144, 2048, 4096, 4096};
    ca.cum[0] = 0;
    for (int i = 0; i < 12; i++) ca.cum[i + 1] = ca.cum[i] + segb[i];
    cvtall_k<<<ca.cum[12], 256, 0, stream>>>(ca, wb);

    rmsf_k<<<N, 256, 0, stream>>>(z, w_z, zn, out + 2 * U, nullptr, D);  // + z_before
    rmsf_k<<<N, 256, 0, stream>>>(conn, w_c, cn, nullptr, connb, D);     // + conn bf16

    const u16* nu = nullptr;
    // dz_local = f_w2(silu(f_w1(zn)))
    gemm_t<128, 128, 1><<<dim3(16, 32), 256, 0, stream>>>(
        zn, nu, nu, bf_w1, f_b1, h1, nu, nullptr, nullptr, nullptr, D, 2 * D, 1, 0);
    gemm_t<128, 64, 1><<<dim3(16, 32), 256, 0, stream>>>(
        h1, nu, nu, bf_w2, f_b2, dzl, nu, nullptr, nullptr, nullptr, 2 * D, D, 0, 0);
    // corr path; g_w2 epilogue writes dz = dt*(dzl + corr) directly (mode 2)
    gemm_t<128, 64, 2><<<dim3(16, 32), 256, 0, stream>>>(
        cn, dzl, nu, bg_w1, g_b1, gh, nu, nullptr, nullptr, nullptr, 2 * D, D, 2, 0);
    gemm_t<128, 64, 1><<<dim3(16, 32), 256, 0, stream>>>(
        gh, nu, nu, bg_w2, g_b2, dz, dzl, nullptr, dt_p, nullptr, D, D, 0, 2);

    // attention: fused Q|K, V-transpose, sigmoid attn, o-proj (+z1 fusion)
    gemm_t<128, 128, 2><<<dim3(16, 32), 256, 0, stream>>>(
        zn, cn, nu, bqk_w, nullptr, QK, nu, nullptr, nullptr, nullptr, 2 * D, 2 * D, 0, 0);
    gemm_t<128, 64, 1><<<dim3(16, 32), 256, 0, stream>>>(
        zn, nu, nu, bv_w, nullptr, VT, nu, nullptr, nullptr, nullptr, D, D, 0, 1);
    attn_k<<<B * H * L / 64, 256, 0, stream>>>(QK, VT, temp_p, attnb);
    gemm_t<128, 64, 1><<<dim3(16, 32), 256, 0, stream>>>(       // z1 = z + dz + ctx
        attnb, nu, nu, bo_w, nullptr, z1, dz, z, nullptr, nullptr, D, D, 0, 3);

    // connection update; cu_w2 epilogue writes conn_new (fp32) directly
    gemm_t<128, 128, 3><<<dim3(16, 32), 256, 0, stream>>>(
        connb, z1, dz, bcu_w1, cu_b1, cu_h, nu, nullptr, nullptr, nullptr, 3 * D, 2 * D, 1, 0);
    gemm_t<128, 64, 1><<<dim3(16, 32), 256, 0, stream>>>(
        cu_h, nu, nu, bcu_w2, cu_b2, (u16*)nullptr, nu, conn, nullptr, out + U, 2 * D, D, 0, 4);

    // MLP block; m_w2 epilogue writes z2 (fp32) directly
    rmsb_k<<<N, 256, 0, stream>>>(z1, w_mlp, z1n, D);
    gemm_t<128, 128, 1><<<dim3(32, 32), 256, 0, stream>>>(
        z1n, nu, nu, bm_w1, m_b1, mh, nu, nullptr, nullptr, nullptr, D, 4 * D, 1, 0);
    gemm_t<128, 64, 1><<<dim3(16, 32), 256, 0, stream>>>(
        mh, nu, nu, bm_w2, m_b2, (u16*)nullptr, z1, nullptr, nullptr, out, 4 * D, D, 0, 5);
}